// Round 12
// baseline (184.327 us; speedup 1.0000x reference)
//
#include <hip/hip_runtime.h>

#define BATCH  8192
#define LATENT 128
#define HID    400
#define HIDP   448   // 7*64, zero-padded K for layer 2
#define NOUT   4096
#define NE     16
#define HROWS  (BATCH + 256)   // padded rows so layer-2 A-staging never reads OOB

typedef __attribute__((ext_vector_type(8))) short bf16x8;
typedef __attribute__((ext_vector_type(4))) float f32x4;

__device__ __forceinline__ unsigned short f2bf(float f){
  unsigned u = __builtin_bit_cast(unsigned, f);
  u += 0x7fffu + ((u >> 16) & 1u);            // round-to-nearest-even
  return (unsigned short)(u >> 16);
}

__device__ __forceinline__ void gload16(const void* g, void* l){
  __builtin_amdgcn_global_load_lds(
      (const __attribute__((address_space(1))) void*)g,
      (__attribute__((address_space(3))) void*)l, 16, 0, 0);
}

__device__ __forceinline__ void convert_rows(const float* __restrict__ W2,
                                             unsigned short* __restrict__ W2b,
                                             int row, int slot){
  if (slot >= 56) return;
  int k = slot*8;
  bf16x8 w = (bf16x8){0,0,0,0,0,0,0,0};
  if (k < HID){
    const float* s = W2 + (size_t)row*HID + k;
    f32x4 a = __builtin_nontemporal_load((const f32x4*)s);
    f32x4 b = __builtin_nontemporal_load((const f32x4*)(s+4));
    w[0]=(short)f2bf(a.x); w[1]=(short)f2bf(a.y); w[2]=(short)f2bf(a.z); w[3]=(short)f2bf(a.w);
    w[4]=(short)f2bf(b.x); w[5]=(short)f2bf(b.y); w[6]=(short)f2bf(b.z); w[7]=(short)f2bf(b.w);
  }
  __builtin_nontemporal_store(w, (bf16x8*)(W2b + (size_t)row*HIDP + k));
}

// ---------------- bucketing: hist + scan + scatter, one block ----------------
__global__ __launch_bounds__(1024) void k_bucket(const int* __restrict__ aidx, int* __restrict__ wsI){
  __shared__ int hist[NE];
  __shared__ int cursor[NE];
  int tid = threadIdx.x, lane = tid & 63;
  if (tid < NE) hist[tid] = 0;
  __syncthreads();

  int ev[8];
  #pragma unroll
  for (int c=0;c<8;c++) ev[c] = aidx[c*1024 + tid];

  #pragma unroll
  for (int c=0;c<8;c++){
    for (int x=0;x<NE;x++){
      unsigned long long m = __ballot(ev[c]==x);
      if (lane==0 && m) atomicAdd(&hist[x], (int)__popcll(m));
    }
  }
  __syncthreads();
  if (tid==0){
    int a=0;
    for (int x=0;x<NE;x++){ cursor[x]=a; wsI[32+x]=a; a+=hist[x]; }
    wsI[32+NE]=a;
  }
  __syncthreads();

  #pragma unroll
  for (int c=0;c<8;c++){
    int e = ev[c], i = c*1024 + tid;
    for (int x=0;x<NE;x++){
      unsigned long long m = __ballot(e==x);
      if (m){
        int leader = __ffsll((unsigned long long)m) - 1;
        int base = 0;
        if (lane == leader) base = atomicAdd(&cursor[x], (int)__popcll(m));
        base = __shfl(base, leader);
        if (e==x){
          int rank = (int)__popcll(m & ((1ull<<lane)-1ull));
          wsI[64 + base + rank] = i;
        }
      }
    }
  }
}

// ---------------- mid: blocks 0..1007 = layer1; blocks 1008.. = FULL W2 convert ----------------
__global__ __launch_bounds__(256) void k_mid(
    const float* __restrict__ z, const float* __restrict__ W1, const float* __restrict__ b1,
    const int* __restrict__ wsI, unsigned short* __restrict__ hws,
    const float* __restrict__ W2, unsigned short* __restrict__ W2b)
{
  int tid = threadIdx.x;
  if (blockIdx.x >= 1008){
    int row = (int)(blockIdx.x - 1008)*4 + (tid>>6);   // 16384 blocks x 4 rows = 65536
    convert_rows(W2, W2b, row, tid & 63);
    return;
  }

  // ---- layer 1: h = relu(z @ W1[e]^T + b1[e]) ----
  __shared__ int s_off[NE+1];
  __shared__ int s_perm[64];
  __shared__ unsigned short As[64*128];
  __shared__ unsigned short Bs[64*128];
  if (tid <= NE) s_off[tid] = wsI[32+tid];
  __syncthreads();

  int rt = (int)blockIdx.x / 7;
  int n0 = ((int)blockIdx.x % 7) * 64;

  int e=-1, tile=0;
  { int acc=0;
    for (int i=0;i<NE;i++){
      int cnt = s_off[i+1]-s_off[i]; int t = (cnt+63)>>6;
      if (rt < acc+t){ e=i; tile=rt-acc; break; }
      acc += t; } }
  if (e < 0) return;
  int r0 = s_off[e] + tile*64;
  int rows = s_off[e+1] - r0; if (rows > 64) rows = 64;

  if (tid < 64) s_perm[tid] = (tid < rows) ? wsI[64 + r0 + tid] : 0;
  __syncthreads();

  #pragma unroll
  for (int p=0;p<8;p++){
    int id = tid + p*256; int row = id>>5, c4 = id&31;
    float4 v = make_float4(0.f,0.f,0.f,0.f);
    if (row < rows) v = *(const float4*)(z + (size_t)s_perm[row]*LATENT + c4*4);
    short4 w; w.x=(short)f2bf(v.x); w.y=(short)f2bf(v.y); w.z=(short)f2bf(v.z); w.w=(short)f2bf(v.w);
    *(short4*)((char*)As + row*256 + ((c4*8) ^ ((row&7)<<4))) = w;
  }
  const float* w1e = W1 + (size_t)e*HID*LATENT;
  #pragma unroll
  for (int p=0;p<8;p++){
    int id = tid + p*256; int row = id>>5, c4 = id&31;
    int n = n0 + row;
    float4 v = make_float4(0.f,0.f,0.f,0.f);
    if (n < HID) v = *(const float4*)(w1e + (size_t)n*LATENT + c4*4);
    short4 w; w.x=(short)f2bf(v.x); w.y=(short)f2bf(v.y); w.z=(short)f2bf(v.z); w.w=(short)f2bf(v.w);
    *(short4*)((char*)Bs + row*256 + ((c4*8) ^ ((row&7)<<4))) = w;
  }
  __syncthreads();

  int lane = tid & 63, wid = tid >> 6;
  int wm = wid >> 1, wn = wid & 1;
  int llo = lane & 15, lhi = lane >> 4;
  f32x4 acc[2][2];
  #pragma unroll
  for (int i=0;i<2;i++)
    #pragma unroll
    for (int j=0;j<2;j++) acc[i][j] = (f32x4){0.f,0.f,0.f,0.f};

  #pragma unroll
  for (int s=0;s<4;s++){
    bf16x8 af[2], bfr[2];
    #pragma unroll
    for (int i=0;i<2;i++){ int m = wm*32 + i*16 + llo;
      af[i] = *(bf16x8*)((char*)As + m*256 + ((s*64 + lhi*16) ^ ((m&7)<<4))); }
    #pragma unroll
    for (int j=0;j<2;j++){ int n = wn*32 + j*16 + llo;
      bfr[j] = *(bf16x8*)((char*)Bs + n*256 + ((s*64 + lhi*16) ^ ((n&7)<<4))); }
    #pragma unroll
    for (int i=0;i<2;i++)
      #pragma unroll
      for (int j=0;j<2;j++)
        acc[i][j] = __builtin_amdgcn_mfma_f32_16x16x32_bf16(af[i], bfr[j], acc[i][j], 0,0,0);
  }

  const float* b1e = b1 + e*HID;
  #pragma unroll
  for (int i=0;i<2;i++){
    #pragma unroll
    for (int j=0;j<2;j++){
      int n = n0 + wn*32 + j*16 + llo;
      float bias = (n < HID) ? b1e[n] : 0.f;
      #pragma unroll
      for (int q=0;q<4;q++){
        int m = wm*32 + i*16 + lhi*4 + q;
        if (m < rows){
          float v = acc[i][j][q] + bias;
          v = (v > 0.f) ? v : 0.f;
          if (n >= HID) v = 0.f;
          hws[(size_t)(r0+m)*HIDP + n] = f2bf(v);
        }
      }
    }
  }
}

// ---------------- layer 2: out = sigmoid(h @ W2b[e]^T + b2[e]) ----------------
// 128x128 tile, BK=64 (7 iters), 4 waves 2x2, dbuf gload_lds (pre-swizzled src),
// counted vmcnt BEFORE use: STAGE(next) -> vmcnt(8) -> barrier -> MFMA -> barrier.
// XCD-chunked block swizzle (2560 = 8*320, bijective). nt stores for out.
__global__ __launch_bounds__(256) void k_layer2(
    const unsigned short* __restrict__ hws, const unsigned short* __restrict__ W2b,
    const float* __restrict__ b2, const int* __restrict__ wsI, float* __restrict__ out)
{
  __shared__ int s_off[NE+1];
  __shared__ int s_perm[128];
  __shared__ unsigned short As[2][128*64];
  __shared__ unsigned short Bs[2][128*64];
  int tid = threadIdx.x;
  if (tid <= NE) s_off[tid] = wsI[32+tid];
  __syncthreads();

  int lin = (int)blockIdx.x;
  int logical = (lin & 7) * 320 + (lin >> 3);
  int bx = logical % 80, by = logical / 80;

  int e=-1, tile=0;
  { int acc=0;
    for (int i=0;i<NE;i++){
      int cnt = s_off[i+1]-s_off[i]; int t = (cnt+127)>>7;
      if (bx < acc+t){ e=i; tile=bx-acc; break; }
      acc += t; } }
  if (e < 0) return;
  int r0 = s_off[e] + tile*128;
  int rows = s_off[e+1] - r0; if (rows > 128) rows = 128;
  int n0 = by * 128;
  if (tid < 128) s_perm[tid] = (tid < rows) ? wsI[64 + r0 + tid] : 0;

  int lane = tid & 63, w = tid >> 6;
  // staging: 16 chunks of 1KB per matrix; wave w stages chunks w*4+p.
  // dest linear; source col unit pre-swizzled: colU = (lane&7) ^ (lane>>3).
  int srow = lane >> 3;
  int colU = (lane & 7) ^ srow;
  const unsigned short* aSrcBase = hws + (size_t)r0*HIDP + colU*8;
  const unsigned short* bSrcBase = W2b + ((size_t)e*NOUT + n0)*HIDP + colU*8;

  int wm = w >> 1, wn = w & 1;
  int llo = lane & 15, lhi = lane >> 4;
  f32x4 acc[4][4];
  #pragma unroll
  for (int i=0;i<4;i++)
    #pragma unroll
    for (int j=0;j<4;j++) acc[i][j] = (f32x4){0.f,0.f,0.f,0.f};

  #define STAGE(BUF, K0) { _Pragma("unroll") for (int p=0;p<4;p++){ \
      int c = w*4 + p; int row = c*8 + srow; \
      gload16(aSrcBase + (size_t)row*HIDP + (K0), &As[BUF][c*512]); \
      gload16(bSrcBase + (size_t)row*HIDP + (K0), &Bs[BUF][c*512]); } }

  STAGE(0, 0);                                         // 8 loads in flight

  int cur = 0;
  for (int kt=0; kt<7; kt++){
    if (kt < 6){
      STAGE(cur^1, (kt+1)*64);                         // +8 loads (next tile)
      asm volatile("s_waitcnt vmcnt(8)" ::: "memory"); // cur's 8 landed; next's in flight
    } else {
      asm volatile("s_waitcnt vmcnt(0)" ::: "memory");
    }
    __builtin_amdgcn_s_barrier();                      // all waves' cur-tile writes visible
    #pragma unroll
    for (int s=0;s<2;s++){
      bf16x8 af[4], bfr[4];
      #pragma unroll
      for (int i=0;i<4;i++){ int m = wm*64 + i*16 + llo;
        af[i] = *(bf16x8*)((char*)&As[cur][0] + m*128 + ((s*64 + lhi*16) ^ ((m&7)<<4))); }
      #pragma unroll
      for (int j=0;j<4;j++){ int n = wn*64 + j*16 + llo;
        bfr[j] = *(bf16x8*)((char*)&Bs[cur][0] + n*128 + ((s*64 + lhi*16) ^ ((n&7)<<4))); }
      #pragma unroll
      for (int i=0;i<4;i++)
        #pragma unroll
        for (int j=0;j<4;j++)
          acc[i][j] = __builtin_amdgcn_mfma_f32_16x16x32_bf16(af[i], bfr[j], acc[i][j], 0,0,0);
    }
    __builtin_amdgcn_s_barrier();                      // done reading cur before overwrite
    cur ^= 1;
  }

  const float* b2e = b2 + e*NOUT;
  #pragma unroll
  for (int i=0;i<4;i++){
    int mb = wm*64 + i*16 + lhi*4;
    #pragma unroll
    for (int q=0;q<4;q++){
      int m = mb + q;
      if (m < rows){
        int orow = s_perm[m];
        float* op = out + (size_t)orow*NOUT + n0;
        #pragma unroll
        for (int j=0;j<4;j++){
          int nloc = wn*64 + j*16 + llo;
          float x = acc[i][j][q] + b2e[n0 + nloc];
          __builtin_nontemporal_store(1.f / (1.f + __expf(-x)), op + nloc);
        }
      }
    }
  }
}

extern "C" void kernel_launch(void* const* d_in, const int* in_sizes, int n_in,
                              void* d_out, int out_size, void* d_ws, size_t ws_size,
                              hipStream_t stream){
  const float* z   = (const float*)d_in[0];
  const float* W1  = (const float*)d_in[1];
  const float* b1  = (const float*)d_in[2];
  const float* W2  = (const float*)d_in[3];
  const float* b2  = (const float*)d_in[4];
  const int*  aidx = (const int*)d_in[5];
  float* out = (float*)d_out;
  int* wsI = (int*)d_ws;
  unsigned short* hws = (unsigned short*)((char*)d_ws + 65536);
  unsigned short* W2b = (unsigned short*)((char*)d_ws + 65536 + (size_t)HROWS*HIDP*2);

  k_bucket<<<1, 1024, 0, stream>>>(aidx, wsI);
  k_mid   <<<1008 + 16384, 256, 0, stream>>>(z, W1, b1, wsI, hws, W2, W2b); // layer1 || full convert
  k_layer2<<<2560, 256, 0, stream>>>(hws, W2b, b2, wsI, out);
}

// Round 13
// 162.296 us; speedup vs baseline: 1.1357x; 1.1357x over previous
//
#include <hip/hip_runtime.h>

#define BATCH  8192
#define LATENT 128
#define HID    400
#define HIDP   448   // 7*64, zero-padded K used by h only
#define NOUT   4096
#define NE     16
#define HROWS  (BATCH + 256)

typedef __attribute__((ext_vector_type(8))) short bf16x8;
typedef __attribute__((ext_vector_type(4))) float f32x4;
typedef __attribute__((ext_vector_type(4))) unsigned u32x4;

__device__ __forceinline__ unsigned short f2bf(float f){
  unsigned u = __builtin_bit_cast(unsigned, f);
  u += 0x7fffu + ((u >> 16) & 1u);            // round-to-nearest-even
  return (unsigned short)(u >> 16);
}

__device__ __forceinline__ void gload16(const void* g, void* l){
  __builtin_amdgcn_global_load_lds(
      (const __attribute__((address_space(1))) void*)g,
      (__attribute__((address_space(3))) void*)l, 16, 0, 0);
}

// pack(bf16_trunc(a), bf16_trunc(b)) -> one u32 (a in low half = element 2i)
__device__ __forceinline__ unsigned pkbf(float a, float b){
  return __builtin_amdgcn_perm(__builtin_bit_cast(unsigned, b),
                               __builtin_bit_cast(unsigned, a), 0x07060302u);
}

// ---------------- bucketing: hist + scan + scatter, one block ----------------
__global__ __launch_bounds__(1024) void k_bucket(const int* __restrict__ aidx, int* __restrict__ wsI){
  __shared__ int hist[NE];
  __shared__ int cursor[NE];
  int tid = threadIdx.x, lane = tid & 63;
  if (tid < NE) hist[tid] = 0;
  __syncthreads();

  int ev[8];
  #pragma unroll
  for (int c=0;c<8;c++) ev[c] = aidx[c*1024 + tid];

  #pragma unroll
  for (int c=0;c<8;c++){
    for (int x=0;x<NE;x++){
      unsigned long long m = __ballot(ev[c]==x);
      if (lane==0 && m) atomicAdd(&hist[x], (int)__popcll(m));
    }
  }
  __syncthreads();
  if (tid==0){
    int a=0;
    for (int x=0;x<NE;x++){ cursor[x]=a; wsI[32+x]=a; a+=hist[x]; }
    wsI[32+NE]=a;
  }
  __syncthreads();

  #pragma unroll
  for (int c=0;c<8;c++){
    int e = ev[c], i = c*1024 + tid;
    for (int x=0;x<NE;x++){
      unsigned long long m = __ballot(e==x);
      if (m){
        int leader = __ffsll((unsigned long long)m) - 1;
        int base = 0;
        if (lane == leader) base = atomicAdd(&cursor[x], (int)__popcll(m));
        base = __shfl(base, leader);
        if (e==x){
          int rank = (int)__popcll(m & ((1ull<<lane)-1ull));
          wsI[64 + base + rank] = i;
        }
      }
    }
  }
}

// ---------------- layer 1: h = relu(z @ W1[e]^T + b1[e]) ----------------
__global__ __launch_bounds__(256) void k_layer1(
    const float* __restrict__ z, const float* __restrict__ W1, const float* __restrict__ b1,
    const int* __restrict__ wsI, unsigned short* __restrict__ hws)
{
  __shared__ int s_off[NE+1];
  __shared__ int s_perm[64];
  __shared__ unsigned short As[64*128];
  __shared__ unsigned short Bs[64*128];
  int tid = threadIdx.x;
  if (tid <= NE) s_off[tid] = wsI[32+tid];
  __syncthreads();

  int e=-1, tile=0;
  { int acc=0;
    for (int i=0;i<NE;i++){
      int cnt = s_off[i+1]-s_off[i]; int t = (cnt+63)>>6;
      if ((int)blockIdx.x < acc+t){ e=i; tile=(int)blockIdx.x-acc; break; }
      acc += t; } }
  if (e < 0) return;
  int r0 = s_off[e] + tile*64;
  int rows = s_off[e+1] - r0; if (rows > 64) rows = 64;
  int n0 = blockIdx.y * 64;

  if (tid < 64) s_perm[tid] = (tid < rows) ? wsI[64 + r0 + tid] : 0;
  __syncthreads();

  #pragma unroll
  for (int p=0;p<8;p++){
    int id = tid + p*256; int row = id>>5, c4 = id&31;
    float4 v = make_float4(0.f,0.f,0.f,0.f);
    if (row < rows) v = *(const float4*)(z + (size_t)s_perm[row]*LATENT + c4*4);
    short4 w; w.x=(short)f2bf(v.x); w.y=(short)f2bf(v.y); w.z=(short)f2bf(v.z); w.w=(short)f2bf(v.w);
    *(short4*)((char*)As + row*256 + ((c4*8) ^ ((row&7)<<4))) = w;
  }
  const float* w1e = W1 + (size_t)e*HID*LATENT;
  #pragma unroll
  for (int p=0;p<8;p++){
    int id = tid + p*256; int row = id>>5, c4 = id&31;
    int n = n0 + row;
    float4 v = make_float4(0.f,0.f,0.f,0.f);
    if (n < HID) v = *(const float4*)(w1e + (size_t)n*LATENT + c4*4);
    short4 w; w.x=(short)f2bf(v.x); w.y=(short)f2bf(v.y); w.z=(short)f2bf(v.z); w.w=(short)f2bf(v.w);
    *(short4*)((char*)Bs + row*256 + ((c4*8) ^ ((row&7)<<4))) = w;
  }
  __syncthreads();

  int lane = tid & 63, wid = tid >> 6;
  int wm = wid >> 1, wn = wid & 1;
  int llo = lane & 15, lhi = lane >> 4;
  f32x4 acc[2][2];
  #pragma unroll
  for (int i=0;i<2;i++)
    #pragma unroll
    for (int j=0;j<2;j++) acc[i][j] = (f32x4){0.f,0.f,0.f,0.f};

  #pragma unroll
  for (int s=0;s<4;s++){
    bf16x8 af[2], bfr[2];
    #pragma unroll
    for (int i=0;i<2;i++){ int m = wm*32 + i*16 + llo;
      af[i] = *(bf16x8*)((char*)As + m*256 + ((s*64 + lhi*16) ^ ((m&7)<<4))); }
    #pragma unroll
    for (int j=0;j<2;j++){ int n = wn*32 + j*16 + llo;
      bfr[j] = *(bf16x8*)((char*)Bs + n*256 + ((s*64 + lhi*16) ^ ((n&7)<<4))); }
    #pragma unroll
    for (int i=0;i<2;i++)
      #pragma unroll
      for (int j=0;j<2;j++)
        acc[i][j] = __builtin_amdgcn_mfma_f32_16x16x32_bf16(af[i], bfr[j], acc[i][j], 0,0,0);
  }

  const float* b1e = b1 + e*HID;
  #pragma unroll
  for (int i=0;i<2;i++){
    #pragma unroll
    for (int j=0;j<2;j++){
      int n = n0 + wn*32 + j*16 + llo;
      float bias = (n < HID) ? b1e[n] : 0.f;
      #pragma unroll
      for (int q=0;q<4;q++){
        int m = wm*32 + i*16 + lhi*4 + q;
        if (m < rows){
          float v = acc[i][j][q] + bias;
          v = (v > 0.f) ? v : 0.f;
          if (n >= HID) v = 0.f;
          hws[(size_t)(r0+m)*HIDP + n] = f2bf(v);
        }
      }
    }
  }
}

// ---------------- layer 2: out = sigmoid(h @ W2[e]^T + b2[e]) ----------------
// NO W2b intermediate: B staged as raw fp32 via gload16 (dbuf, counted vmcnt),
// converted to bf16 at fragment read (ds_read_b128 x2 + v_perm truncate-pack).
// 128x128 tile, BK=32, 13 K-steps; LDS 48.7 KB -> 3 blocks/CU. XCD-chunked grid.
// Swizzles: A (64B rows) unit^=((row>>1)&3); B (128B fp32 rows) unit^=(row&7).
__global__ __launch_bounds__(256) void k_layer2(
    const unsigned short* __restrict__ hws, const float* __restrict__ W2,
    const float* __restrict__ b2, const int* __restrict__ wsI, float* __restrict__ out)
{
  __shared__ int s_off[NE+1];
  __shared__ int s_perm[128];
  __shared__ unsigned short As[2][128*32];   // 8 KB each
  __shared__ float Bs[2][128*32];            // 16 KB each
  int tid = threadIdx.x;
  if (tid <= NE) s_off[tid] = wsI[32+tid];
  __syncthreads();

  int lin = (int)blockIdx.x;
  int logical = (lin & 7) * 320 + (lin >> 3);
  int bx = logical % 80, by = logical / 80;

  int e=-1, tile=0;
  { int acc=0;
    for (int i=0;i<NE;i++){
      int cnt = s_off[i+1]-s_off[i]; int t = (cnt+127)>>7;
      if (bx < acc+t){ e=i; tile=bx-acc; break; }
      acc += t; } }
  if (e < 0) return;
  int r0 = s_off[e] + tile*128;
  int rows = s_off[e+1] - r0; if (rows > 128) rows = 128;
  int n0 = by * 128;
  if (tid < 128) s_perm[tid] = (tid < rows) ? wsI[64 + r0 + tid] : 0;

  // ---- staging geometry (per thread, constant across iters) ----
  // A: 2 slots a = tid + p*256; r=a>>2, u=a&3; src colU = u ^ ((r>>1)&3)
  // B: 4 slots s = tid + p*256; r=s>>3, u=s&7; src colU = u ^ (r&7)
  const unsigned short* aBase[2];
  #pragma unroll
  for (int p=0;p<2;p++){
    int a = tid + p*256; int r = a>>2, u = a&3;
    int cu = u ^ ((r>>1)&3);
    aBase[p] = hws + (size_t)(r0 + r)*HIDP + cu*8;
  }
  const float* bBase[4];
  int bAdj[4];
  #pragma unroll
  for (int p=0;p<4;p++){
    int s = tid + p*256; int r = s>>3, u = s&7;
    int cu = u ^ (r&7);
    bBase[p] = W2 + ((size_t)e*NOUT + n0 + r)*HID + cu*4;
    bAdj[p] = (cu >= 4) ? -16 : 0;            // last tile: k=384+cu*4 would pass 400
  }

  int lane = tid & 63, w = tid >> 6;
  int wm = w >> 1, wn = w & 1;
  int llo = lane & 15, lhi = lane >> 4;
  f32x4 acc[4][4];
  #pragma unroll
  for (int i=0;i<4;i++)
    #pragma unroll
    for (int j=0;j<4;j++) acc[i][j] = (f32x4){0.f,0.f,0.f,0.f};

  #define STAGE(BUF, K0, LAST) { \
    _Pragma("unroll") for (int p=0;p<2;p++){ \
      int a = tid + p*256; \
      gload16(aBase[p] + (K0), &As[BUF][a*8]); } \
    _Pragma("unroll") for (int p=0;p<4;p++){ \
      int s = tid + p*256; \
      gload16(bBase[p] + (K0) + ((LAST) ? bAdj[p] : 0), &Bs[BUF][s*4]); } }

  STAGE(0, 0, 0);                                      // 6 loads in flight

  int cur = 0;
  for (int kt=0; kt<13; kt++){
    if (kt < 12){
      STAGE(cur^1, (kt+1)*32, (kt+1)==12);             // +6 (next tile)
      asm volatile("s_waitcnt vmcnt(6)" ::: "memory"); // cur's 6 landed; next's in flight
    } else {
      asm volatile("s_waitcnt vmcnt(0)" ::: "memory");
    }
    __builtin_amdgcn_s_barrier();

    bf16x8 af[4], bfr[4];
    #pragma unroll
    for (int i=0;i<4;i++){ int m = wm*64 + i*16 + llo;
      af[i] = *(bf16x8*)((char*)&As[cur][0] + m*64 + ((lhi*16) ^ (((m>>1)&3)<<4))); }
    #pragma unroll
    for (int j=0;j<4;j++){
      int n = wn*64 + j*16 + llo;
      const char* bp = (const char*)&Bs[cur][0] + n*128;
      f32x4 lo = *(const f32x4*)(bp + (((2*lhi+0)*16) ^ ((n&7)<<4)));
      f32x4 hi = *(const f32x4*)(bp + (((2*lhi+1)*16) ^ ((n&7)<<4)));
      u32x4 pk;
      pk.x = pkbf(lo.x, lo.y); pk.y = pkbf(lo.z, lo.w);
      pk.z = pkbf(hi.x, hi.y); pk.w = pkbf(hi.z, hi.w);
      if (kt == 12 && lhi >= 2) pk = (u32x4){0,0,0,0};  // k >= 400
      bfr[j] = __builtin_bit_cast(bf16x8, pk);
    }
    #pragma unroll
    for (int i=0;i<4;i++)
      #pragma unroll
      for (int j=0;j<4;j++)
        acc[i][j] = __builtin_amdgcn_mfma_f32_16x16x32_bf16(af[i], bfr[j], acc[i][j], 0,0,0);

    __builtin_amdgcn_s_barrier();
    cur ^= 1;
  }

  const float* b2e = b2 + (size_t)e*NOUT;
  #pragma unroll
  for (int i=0;i<4;i++){
    int mb = wm*64 + i*16 + lhi*4;
    #pragma unroll
    for (int q=0;q<4;q++){
      int m = mb + q;
      if (m < rows){
        int orow = s_perm[m];
        float* op = out + (size_t)orow*NOUT + n0;
        #pragma unroll
        for (int j=0;j<4;j++){
          int nloc = wn*64 + j*16 + llo;
          float x = acc[i][j][q] + b2e[n0 + nloc];
          __builtin_nontemporal_store(1.f / (1.f + __expf(-x)), op + nloc);
        }
      }
    }
  }
}

extern "C" void kernel_launch(void* const* d_in, const int* in_sizes, int n_in,
                              void* d_out, int out_size, void* d_ws, size_t ws_size,
                              hipStream_t stream){
  const float* z   = (const float*)d_in[0];
  const float* W1  = (const float*)d_in[1];
  const float* b1  = (const float*)d_in[2];
  const float* W2  = (const float*)d_in[3];
  const float* b2  = (const float*)d_in[4];
  const int*  aidx = (const int*)d_in[5];
  float* out = (float*)d_out;
  int* wsI = (int*)d_ws;
  unsigned short* hws = (unsigned short*)((char*)d_ws + 65536);

  k_bucket<<<1, 1024, 0, stream>>>(aidx, wsI);
  k_layer1<<<dim3(144, 7), 256, 0, stream>>>(z, W1, b1, wsI, hws);
  k_layer2<<<2560, 256, 0, stream>>>(hws, W2, b2, wsI, out);
}